// Round 3
// baseline (551.009 us; speedup 1.0000x reference)
//
#include <hip/hip_runtime.h>
#include <hip/hip_bf16.h>
#include <math.h>

// Problem constants (from reference)
constexpr int B_  = 4;
constexpr int NQ_ = 2048;
constexpr int NK_ = 2048;
constexpr int C_  = 4;
constexpr int OUT_ = 64;
constexpr int H_  = 16;
constexpr float WINDOW_ = 0.25f;

// One block per (b,q). 256 threads, each handles 8 keys as 2 passes of 4
// contiguous keys (4-key batching amortizes uniform weight loads; weights
// come in as scalar loads -> SGPR operands of v_fmac, inner loop pure VALU).
// Dtypes: ALL float tensors are fp32 (per reference setup_inputs), output
// fp32. Evidence: round-1 (fp32 reads, bf16 writes) gave bounded 0.689;
// round-2 (bf16 reads) gave NaN — only fp32-in/fp32-out explains both.
__global__ __launch_bounds__(256, 2) void setconv_fused(
    const float* __restrict__ key_pos,
    const float* __restrict__ queries,
    const float* __restrict__ values,
    const int*   __restrict__ key_chan,
    const float* __restrict__ w0, const float* __restrict__ b0,
    const float* __restrict__ w1, const float* __restrict__ b1,
    const float* __restrict__ w2, const float* __restrict__ b2,
    const float* __restrict__ w3, const float* __restrict__ b3,
    const float* __restrict__ wd, const float* __restrict__ bd,
    const float* __restrict__ wr, const float* __restrict__ br,
    float* __restrict__ out)
{
    const int tid = threadIdx.x;
    const int bq  = blockIdx.x;          // 0 .. B*NQ-1
    const int b   = bq >> 11;            // / NQ_

    const float qpos = queries[bq];

    float dens[C_] = {0.f, 0.f, 0.f, 0.f};
    float num [C_] = {0.f, 0.f, 0.f, 0.f};

    #pragma unroll
    for (int pass = 0; pass < 2; ++pass) {
        // 4 contiguous keys per thread -> float4 loads merge to dwordx4
        const int kbase = b * NK_ + pass * 1024 + tid * 4;

        float diff[4];
        #pragma unroll
        for (int c = 0; c < 4; ++c)
            diff[c] = fabsf(key_pos[kbase + c] - qpos);

        float h[4][H_], g[4][H_];

        // layer 0: 1 -> 16, ReLU
        #pragma unroll
        for (int i = 0; i < H_; ++i) {
            const float wv = w0[i];
            const float bv = b0[i];
            #pragma unroll
            for (int c = 0; c < 4; ++c)
                h[c][i] = fmaxf(fmaf(diff[c], wv, bv), 0.f);
        }
        // layer 1: 16 -> 16, ReLU
        #pragma unroll
        for (int j = 0; j < H_; ++j) {
            const float bv = b1[j];
            float acc[4] = {bv, bv, bv, bv};
            #pragma unroll
            for (int i = 0; i < H_; ++i) {
                const float wv = w1[j * H_ + i];
                #pragma unroll
                for (int c = 0; c < 4; ++c)
                    acc[c] = fmaf(wv, h[c][i], acc[c]);
            }
            #pragma unroll
            for (int c = 0; c < 4; ++c) g[c][j] = fmaxf(acc[c], 0.f);
        }
        // layer 2: 16 -> 16, ReLU (back into h)
        #pragma unroll
        for (int j = 0; j < H_; ++j) {
            const float bv = b2[j];
            float acc[4] = {bv, bv, bv, bv};
            #pragma unroll
            for (int i = 0; i < H_; ++i) {
                const float wv = w2[j * H_ + i];
                #pragma unroll
                for (int c = 0; c < 4; ++c)
                    acc[c] = fmaf(wv, g[c][i], acc[c]);
            }
            #pragma unroll
            for (int c = 0; c < 4; ++c) h[c][j] = fmaxf(acc[c], 0.f);
        }
        // output layer: 16 -> 1
        const float b3v = b3[0];
        float raw[4] = {b3v, b3v, b3v, b3v};
        #pragma unroll
        for (int i = 0; i < H_; ++i) {
            const float wv = w3[i];
            #pragma unroll
            for (int c = 0; c < 4; ++c)
                raw[c] = fmaf(wv, h[c][i], raw[c]);
        }

        // window mask + per-channel accumulate (branchless selects)
        #pragma unroll
        for (int c = 0; c < 4; ++c) {
            const float wgt = (diff[c] < WINDOW_) ? fabsf(raw[c]) : 0.f;
            const int   ch  = key_chan[kbase + c];
            const float v   = values[kbase + c];
            const float wv2 = wgt * v;
            dens[0] += (ch == 0) ? wgt : 0.f;  num[0] += (ch == 0) ? wv2 : 0.f;
            dens[1] += (ch == 1) ? wgt : 0.f;  num[1] += (ch == 1) ? wv2 : 0.f;
            dens[2] += (ch == 2) ? wgt : 0.f;  num[2] += (ch == 2) ? wv2 : 0.f;
            dens[3] += (ch == 3) ? wgt : 0.f;  num[3] += (ch == 3) ? wv2 : 0.f;
        }
    }

    // wave (64-lane) butterfly reduction of the 8 partial sums
    #pragma unroll
    for (int off = 32; off >= 1; off >>= 1) {
        #pragma unroll
        for (int c = 0; c < 4; ++c) {
            dens[c] += __shfl_xor(dens[c], off, 64);
            num [c] += __shfl_xor(num [c], off, 64);
        }
    }

    __shared__ float red[4][8];
    __shared__ float feat[8];
    const int wave = tid >> 6;
    if ((tid & 63) == 0) {
        #pragma unroll
        for (int c = 0; c < 4; ++c) {
            red[wave][c]     = dens[c];
            red[wave][4 + c] = num[c];
        }
    }
    __syncthreads();

    if (tid < 4) {
        const int c = tid;
        const float d = red[0][c] + red[1][c] + red[2][c] + red[3][c];
        const float n = red[0][4+c] + red[1][4+c] + red[2][4+c] + red[3][4+c];
        const float target = n / (d + 1e-5f);
        const float x  = (d * 0.1f - 1.0f) * wd[0] + bd[0];
        const float df = 1.0f / (1.0f + expf(-x));
        feat[2 * c]     = target;
        feat[2 * c + 1] = df;
    }
    __syncthreads();

    // resizer: feat[8] @ wr.T + br -> 64 outputs, one per thread
    if (tid < OUT_) {
        float acc = br[tid];
        #pragma unroll
        for (int j = 0; j < 2 * C_; ++j)
            acc = fmaf(wr[tid * 8 + j], feat[j], acc);
        out[bq * OUT_ + tid] = acc;
    }
}

extern "C" void kernel_launch(void* const* d_in, const int* in_sizes, int n_in,
                              void* d_out, int out_size, void* d_ws, size_t ws_size,
                              hipStream_t stream) {
    (void)in_sizes; (void)n_in; (void)out_size; (void)d_ws; (void)ws_size;
    setconv_fused<<<dim3(B_ * NQ_), dim3(256), 0, stream>>>(
        (const float*)d_in[0],  // key_pos
        (const float*)d_in[1],  // queries
        (const float*)d_in[2],  // values
        (const int*)  d_in[3],  // key_chan
        (const float*)d_in[4],  (const float*)d_in[5],   // w0 b0
        (const float*)d_in[6],  (const float*)d_in[7],   // w1 b1
        (const float*)d_in[8],  (const float*)d_in[9],   // w2 b2
        (const float*)d_in[10], (const float*)d_in[11],  // w3 b3
        (const float*)d_in[12], (const float*)d_in[13],  // wd bd
        (const float*)d_in[14], (const float*)d_in[15],  // wr br
        (float*)d_out);
}

// Round 4
// 108.596 us; speedup vs baseline: 5.0739x; 5.0739x over previous
//
#include <hip/hip_runtime.h>
#include <math.h>

// Problem constants (from reference)
constexpr int B_  = 4;
constexpr int NQ_ = 2048;
constexpr int NK_ = 2048;
constexpr int C_  = 4;
constexpr int OUT_ = 64;
constexpr int H_  = 16;
constexpr float WINDOW_ = 0.25f;

constexpr int   TAB_   = 4096;                 // cells over [0, WINDOW)
constexpr float SCALE_ = TAB_ / WINDOW_;       // 16384
constexpr int   QT_    = 8;                    // queries per block (2 per wave)

// ---------------------------------------------------------------------------
// Kernel 1: the radial MLP is a scalar->scalar ReLU net == piecewise-linear
// (<=48 knots). Tabulate per-cell (intercept a, slope s) so that for diff in
// cell i: f(diff) ~= fma(s_i, diff, a_i). Exact except in knot cells
// (error <= |dslope|*h/4 ~ 1e-4, far under the 1.09e-2 output threshold).
// ---------------------------------------------------------------------------
__global__ void build_tab(
    const float* __restrict__ w0, const float* __restrict__ b0,
    const float* __restrict__ w1, const float* __restrict__ b1,
    const float* __restrict__ w2, const float* __restrict__ b2,
    const float* __restrict__ w3, const float* __restrict__ b3,
    float2* __restrict__ tab)
{
    const int i = blockIdx.x * blockDim.x + threadIdx.x;
    if (i >= TAB_) return;

    float f[2];
    #pragma unroll
    for (int e = 0; e < 2; ++e) {
        const float x = (float)(i + e) * (1.0f / SCALE_);
        float h[H_], g[H_];
        #pragma unroll
        for (int j = 0; j < H_; ++j)
            h[j] = fmaxf(fmaf(x, w0[j], b0[j]), 0.f);
        #pragma unroll
        for (int j = 0; j < H_; ++j) {
            float a = b1[j];
            #pragma unroll
            for (int k = 0; k < H_; ++k) a = fmaf(w1[j * H_ + k], h[k], a);
            g[j] = fmaxf(a, 0.f);
        }
        #pragma unroll
        for (int j = 0; j < H_; ++j) {
            float a = b2[j];
            #pragma unroll
            for (int k = 0; k < H_; ++k) a = fmaf(w2[j * H_ + k], g[k], a);
            h[j] = fmaxf(a, 0.f);
        }
        float a = b3[0];
        #pragma unroll
        for (int k = 0; k < H_; ++k) a = fmaf(w3[k], h[k], a);
        f[e] = a;
    }
    const float s = (f[1] - f[0]) * SCALE_;
    const float a = fmaf(-s, (float)i * (1.0f / SCALE_), f[0]);
    tab[i] = make_float2(a, s);
}

// ---------------------------------------------------------------------------
// Kernel 2: block = 8 queries of one batch; wave = one query (2 per wave).
// Table in LDS (32 KB); per pair ~30 VALU + 1 ds_read_b64 gather.
// Butterfly reduction leaves totals in every lane; lane index == output
// channel (OUT=64 == wave width) for the fused resizer epilogue.
// ---------------------------------------------------------------------------
__global__ __launch_bounds__(256) void setconv_main(
    const float* __restrict__ key_pos,
    const float* __restrict__ queries,
    const float* __restrict__ values,
    const int*   __restrict__ key_chan,
    const float2* __restrict__ tab,
    const float* __restrict__ wd, const float* __restrict__ bd,
    const float* __restrict__ wr, const float* __restrict__ br,
    float* __restrict__ out)
{
    __shared__ __align__(16) float2 ltab[TAB_];

    const int tid = threadIdx.x;

    // stage table: 2048 float4s, 8 per thread
    {
        const float4* t4 = (const float4*)tab;
        float4*       l4 = (float4*)ltab;
        #pragma unroll
        for (int i = 0; i < TAB_ / 2 / 256; ++i)
            l4[i * 256 + tid] = t4[i * 256 + tid];
    }
    __syncthreads();

    const int blk  = blockIdx.x;        // 1024 blocks: b = blk>>8, tile = blk&255
    const int b    = blk >> 8;
    const int tile = blk & 255;
    const int wave = tid >> 6;
    const int lane = tid & 63;

    const float* kpb = key_pos  + b * NK_;
    const float* vb  = values   + b * NK_;
    const int*   cb  = key_chan + b * NK_;

    const float wd0 = wd[0];
    const float bd0 = bd[0];

    // per-lane resizer row (lane == output channel), hoisted across queries
    float wrow[8];
    #pragma unroll
    for (int j = 0; j < 8; ++j) wrow[j] = wr[lane * 8 + j];
    const float brv = br[lane];

    #pragma unroll
    for (int qq = 0; qq < 2; ++qq) {
        const int   qi   = tile * QT_ + wave * 2 + qq;
        const float qpos = queries[b * NQ_ + qi];

        float d0 = 0.f, d1 = 0.f, d2 = 0.f, d3 = 0.f;
        float n0 = 0.f, n1 = 0.f, n2 = 0.f, n3 = 0.f;

        #pragma unroll 4
        for (int it = 0; it < NK_ / 64; ++it) {
            const int   k  = it * 64 + lane;
            const float dd = fabsf(kpb[k] - qpos);
            const float t  = fminf(dd * SCALE_, (float)(TAB_ - 1));
            const int   ci = (int)t;                      // trunc == floor (t>=0)
            const float2 as = ltab[ci];                   // ds_read_b64 gather
            const float raw = fabsf(fmaf(as.y, dd, as.x));
            const float w   = (dd < WINDOW_) ? raw : 0.f; // window mask
            const float wv  = w * vb[k];
            const int   ch  = cb[k];
            const float m0 = (ch == 0) ? 1.f : 0.f;
            const float m1 = (ch == 1) ? 1.f : 0.f;
            const float m2 = (ch == 2) ? 1.f : 0.f;
            const float m3 = (ch == 3) ? 1.f : 0.f;
            d0 = fmaf(m0, w, d0);  n0 = fmaf(m0, wv, n0);
            d1 = fmaf(m1, w, d1);  n1 = fmaf(m1, wv, n1);
            d2 = fmaf(m2, w, d2);  n2 = fmaf(m2, wv, n2);
            d3 = fmaf(m3, w, d3);  n3 = fmaf(m3, wv, n3);
        }

        // 64-lane butterfly: every lane ends with the full sums
        #pragma unroll
        for (int off = 32; off >= 1; off >>= 1) {
            d0 += __shfl_xor(d0, off, 64);  n0 += __shfl_xor(n0, off, 64);
            d1 += __shfl_xor(d1, off, 64);  n1 += __shfl_xor(n1, off, 64);
            d2 += __shfl_xor(d2, off, 64);  n2 += __shfl_xor(n2, off, 64);
            d3 += __shfl_xor(d3, off, 64);  n3 += __shfl_xor(n3, off, 64);
        }

        const float dens[4] = {d0, d1, d2, d3};
        const float num [4] = {n0, n1, n2, n3};

        // fused epilogue, redundantly per lane (cheap); lane = output index
        float acc = brv;
        #pragma unroll
        for (int c = 0; c < 4; ++c) {
            const float tgt = num[c] / (dens[c] + 1e-5f);
            const float x   = (dens[c] * 0.1f - 1.0f) * wd0 + bd0;
            const float df  = 1.0f / (1.0f + expf(-x));
            acc = fmaf(wrow[2 * c],     tgt, acc);
            acc = fmaf(wrow[2 * c + 1], df,  acc);
        }
        out[(b * NQ_ + qi) * OUT_ + lane] = acc;
    }
}

extern "C" void kernel_launch(void* const* d_in, const int* in_sizes, int n_in,
                              void* d_out, int out_size, void* d_ws, size_t ws_size,
                              hipStream_t stream) {
    (void)in_sizes; (void)n_in; (void)out_size; (void)ws_size;

    float2* tab = (float2*)d_ws;   // 4096 * 8 B = 32 KB of scratch

    build_tab<<<dim3((TAB_ + 255) / 256), dim3(256), 0, stream>>>(
        (const float*)d_in[4],  (const float*)d_in[5],   // w0 b0
        (const float*)d_in[6],  (const float*)d_in[7],   // w1 b1
        (const float*)d_in[8],  (const float*)d_in[9],   // w2 b2
        (const float*)d_in[10], (const float*)d_in[11],  // w3 b3
        tab);

    setconv_main<<<dim3(B_ * (NQ_ / QT_)), dim3(256), 0, stream>>>(
        (const float*)d_in[0],  // key_pos
        (const float*)d_in[1],  // queries
        (const float*)d_in[2],  // values
        (const int*)  d_in[3],  // key_chan
        tab,
        (const float*)d_in[12], (const float*)d_in[13],  // wd bd
        (const float*)d_in[14], (const float*)d_in[15],  // wr br
        (float*)d_out);
}